// Round 1
// baseline (283.807 us; speedup 1.0000x reference)
//
#include <hip/hip_runtime.h>
#include <hip/hip_bf16.h>
#include <stdint.h>

typedef unsigned short u16;
typedef unsigned int u32;

using bf16x8 = __attribute__((ext_vector_type(8))) __bf16;  // 4 VGPRs: MFMA A/B operand
using f32x4  = __attribute__((ext_vector_type(4))) float;   // MFMA C/D operand

#define AS1 __attribute__((address_space(1)))
#define AS3 __attribute__((address_space(3)))

// fp32 -> bf16 round-to-nearest-even
__device__ __forceinline__ u16 f2bf(float x) {
  u32 u = __float_as_uint(x);
  u = (u + 0x7FFFu + ((u >> 16) & 1u)) >> 16;
  return (u16)u;
}
__device__ __forceinline__ float bf2f(u32 bits) { return __uint_as_float(bits << 16); }

// async global->LDS, 16B per lane. LDS dest = wave-uniform base + lane*16.
__device__ __forceinline__ void gload16(const void* g, void* l) {
  __builtin_amdgcn_global_load_lds((AS1 void*)(const_cast<void*>(g)),
                                   (AS3 void*)l, 16, 0, 0);
}

// load 16 contiguous bf16 (32B, aligned) into 16 floats
__device__ __forceinline__ void load16bf(const u16* p, float* f) {
  uint4 a = *(const uint4*)(p);
  uint4 b = *(const uint4*)(p + 8);
  u32 v[8] = {a.x, a.y, a.z, a.w, b.x, b.y, b.z, b.w};
#pragma unroll
  for (int i = 0; i < 8; ++i) {
    f[2 * i]     = __uint_as_float(v[i] << 16);
    f[2 * i + 1] = __uint_as_float(v[i] & 0xFFFF0000u);
  }
}

// ---------------------------------------------------------------------------
// Convert / repack all weights to bf16 (scale 2.0 = LORA_SCALE folded into B1,B2;
// A2 transposed to [e][h][r] for contiguous 32B reads per h).
// Segment sizes sum to 11,796,480 = 46080 * 256 exactly.
// ---------------------------------------------------------------------------
__global__ __launch_bounds__(256) void k_cvt(
    const float* __restrict__ hs, const float* __restrict__ W1,
    const float* __restrict__ W2, const float* __restrict__ A1,
    const float* __restrict__ B1, const float* __restrict__ B2,
    const float* __restrict__ A2,
    u16* __restrict__ Xbf, u16* __restrict__ W1bf, u16* __restrict__ W2bf,
    u16* __restrict__ A1bf, u16* __restrict__ B1s, u16* __restrict__ B2s,
    u16* __restrict__ A2t) {
  int i = blockIdx.x * 256 + threadIdx.x;
  if (i < 2097152) { Xbf[i] = f2bf(hs[i]); return; }
  i -= 2097152;
  if (i < 4194304) { W1bf[i] = f2bf(W1[i]); return; }
  i -= 4194304;
  if (i < 4194304) { W2bf[i] = f2bf(W2[i]); return; }
  i -= 4194304;
  if (i < 131072) { A1bf[i] = f2bf(A1[i]); return; }
  i -= 131072;
  if (i < 524288) { B1s[i] = f2bf(2.0f * B1[i]); return; }  // [E,H,R] kept
  i -= 524288;
  if (i < 131072) { B2s[i] = f2bf(2.0f * B2[i]); return; }  // [E,D,R] kept
  i -= 131072;
  // A2 [E,R,H] -> A2t [E,H,R]
  int e = i >> 16, rem = i & 65535, r = rem >> 12, h = rem & 4095;
  A2t[(e << 16) + h * 16 + r] = f2bf(A2[i]);
}

// ---------------------------------------------------------------------------
// Router: 1 wave per token. logits = x . gate[e], top-2, renormalized softmax
// == sigmoid of logit difference.
// ---------------------------------------------------------------------------
__global__ __launch_bounds__(256) void k_router(
    const float* __restrict__ x, const float* __restrict__ gate,
    int* __restrict__ sel, float* __restrict__ wgt) {
  const int lane = threadIdx.x & 63;
  const int wv = threadIdx.x >> 6;
  const int t = blockIdx.x * 4 + wv;
  const float* xp = x + (size_t)t * 1024 + lane * 16;
  float4 xv[4];
#pragma unroll
  for (int i = 0; i < 4; ++i) xv[i] = *(const float4*)(xp + i * 4);
  float acc[8];
#pragma unroll
  for (int e = 0; e < 8; ++e) {
    const float* gp = gate + e * 1024 + lane * 16;
    float s = 0.f;
#pragma unroll
    for (int i = 0; i < 4; ++i) {
      float4 g = *(const float4*)(gp + i * 4);
      s += xv[i].x * g.x + xv[i].y * g.y + xv[i].z * g.z + xv[i].w * g.w;
    }
    acc[e] = s;
  }
#pragma unroll
  for (int e = 0; e < 8; ++e)
    for (int off = 32; off > 0; off >>= 1) acc[e] += __shfl_xor(acc[e], off);
  if (lane == 0) {
    int e0 = 0; float l0 = acc[0];
#pragma unroll
    for (int e = 1; e < 8; ++e) if (acc[e] > l0) { l0 = acc[e]; e0 = e; }
    int e1 = (e0 == 0) ? 1 : 0; float l1 = acc[e1];
#pragma unroll
    for (int e = 0; e < 8; ++e)
      if (e != e0 && acc[e] > l1) { l1 = acc[e]; e1 = e; }
    float p = 1.f / (1.f + __expf(l1 - l0));  // renormalized top-2 softmax
    sel[2 * t] = e0; sel[2 * t + 1] = e1;
    wgt[2 * t] = p;  wgt[2 * t + 1] = 1.f - p;
  }
}

// ---------------------------------------------------------------------------
// bf16 GEMM, C[m,n] = sum_k A[m,k]*B[n,k]  (both row-major [.,K])
// 128x128 tile, BK=64, 256 threads (2x2 waves of 64x64), 16x16x32 MFMA.
// global_load_lds width=16 with XOR chunk swizzle (chunk c of row r lands at
// LDS chunk c^(r&7)) -> ds_read_b128 is 2-way-conflict (free).
// blockIdx.z = split-K slice of Ksub; slice z writes C + z*Cstride_elems.
// ---------------------------------------------------------------------------
__global__ __launch_bounds__(256, 2) void gemm_bt(
    const u16* __restrict__ A, const u16* __restrict__ B, void* __restrict__ Cv,
    int K, int ldc, int Ksub, size_t Cstride_elems, int outbf) {
  __shared__ alignas(16) u16 lsA[128 * 64];
  __shared__ alignas(16) u16 lsB[128 * 64];
  const int tid = threadIdx.x;
  const int lane = tid & 63;
  const int w = tid >> 6;
  const int m0 = blockIdx.x * 128;
  const int n0 = blockIdx.y * 128;
  const int z = blockIdx.z;
  const int wm = w & 1, wn = w >> 1;

  f32x4 acc[4][4] = {};

  // staging: wave w stages rows [w*32, w*32+32) of both tiles; lane i ->
  // row +i/8, LDS chunk i%8, global chunk (i%8)^(r&7)
  const int sr = lane >> 3;
  const int sc = lane & 7;
  const int cg = sc ^ sr;
  const u16* Ag = A + (size_t)(m0 + w * 32 + sr) * K + (size_t)z * Ksub + cg * 8;
  const u16* Bg = B + (size_t)(n0 + w * 32 + sr) * K + (size_t)z * Ksub + cg * 8;
  u16* lA = lsA + w * 2048;  // (w*32 rows) * 64 elems
  u16* lB = lsB + w * 2048;

  const int fr = lane & 15;  // m (A) / n (B) row within 16
  const int fq = lane >> 4;  // k-chunk quad

  for (int kt = 0; kt < Ksub; kt += 64) {
#pragma unroll
    for (int j = 0; j < 4; ++j) {
      gload16(Ag + (size_t)j * 8 * K, lA + j * 512);
      gload16(Bg + (size_t)j * 8 * K, lB + j * 512);
    }
    Ag += 64; Bg += 64;
    __syncthreads();  // drains vmcnt -> LDS writes visible
#pragma unroll
    for (int s = 0; s < 2; ++s) {
      const int cl = (s * 4 + fq) ^ (fr & 7);
      bf16x8 av[4], bv[4];
#pragma unroll
      for (int i = 0; i < 4; ++i)
        av[i] = *(const bf16x8*)&lsA[(wm * 64 + i * 16 + fr) * 64 + cl * 8];
#pragma unroll
      for (int j = 0; j < 4; ++j)
        bv[j] = *(const bf16x8*)&lsB[(wn * 64 + j * 16 + fr) * 64 + cl * 8];
#pragma unroll
      for (int i = 0; i < 4; ++i)
#pragma unroll
        for (int j = 0; j < 4; ++j)
          acc[i][j] = __builtin_amdgcn_mfma_f32_16x16x32_bf16(av[i], bv[j], acc[i][j], 0, 0, 0);
    }
    __syncthreads();
  }

  // D layout: m = fq*4 + reg, n = fr (m89-verified)
  const size_t zoff = (size_t)z * Cstride_elems;
  if (outbf) {
    u16* Co = (u16*)Cv + zoff;
#pragma unroll
    for (int i = 0; i < 4; ++i)
#pragma unroll
      for (int j = 0; j < 4; ++j)
#pragma unroll
        for (int r = 0; r < 4; ++r) {
          int m = m0 + wm * 64 + i * 16 + fq * 4 + r;
          int n = n0 + wn * 64 + j * 16 + fr;
          Co[(size_t)m * ldc + n] = f2bf(acc[i][j][r]);
        }
  } else {
    float* Co = (float*)Cv + zoff;
#pragma unroll
    for (int i = 0; i < 4; ++i)
#pragma unroll
      for (int j = 0; j < 4; ++j)
#pragma unroll
        for (int r = 0; r < 4; ++r) {
          int m = m0 + wm * 64 + i * 16 + fq * 4 + r;
          int n = n0 + wn * 64 + j * 16 + fr;
          Co[(size_t)m * ldc + n] = acc[i][j][r];
        }
  }
}

// ---------------------------------------------------------------------------
// Per token (1 block): fc1 LoRA delta (rank 16) for both selected experts,
// silu, combined activation am = w0*a0 + w1*a1 (bf16), and rank-16 reductions
// T0 = w0 * (a0 @ A2[e0]^T), T1 likewise.
// ---------------------------------------------------------------------------
__global__ __launch_bounds__(256) void k_silu(
    const u16* __restrict__ C1, const float* __restrict__ LX,
    const float* __restrict__ b1, const u16* __restrict__ B1s,
    const u16* __restrict__ A2t, const int* __restrict__ sel,
    const float* __restrict__ wgt, u16* __restrict__ am,
    float* __restrict__ T0, float* __restrict__ T1) {
  const int t = blockIdx.x;
  const int tid = threadIdx.x;
  __shared__ float slx[32];
  __shared__ float sred[2][4][16];
  const int e0 = sel[2 * t], e1 = sel[2 * t + 1];
  const float w0 = wgt[2 * t], w1 = wgt[2 * t + 1];
  if (tid < 32) {
    int e = (tid < 16) ? e0 : e1;
    slx[tid] = LX[t * 128 + e * 16 + (tid & 15)];
  }
  __syncthreads();
  float lx0[16], lx1[16];
#pragma unroll
  for (int r = 0; r < 16; ++r) { lx0[r] = slx[r]; lx1[r] = slx[16 + r]; }
  float t0a[16] = {}, t1a[16] = {};
  const u16* B1e0 = B1s + (size_t)e0 * 65536;
  const u16* B1e1 = B1s + (size_t)e1 * 65536;
  const u16* A2e0 = A2t + (size_t)e0 * 65536;
  const u16* A2e1 = A2t + (size_t)e1 * 65536;

  for (int h = tid; h < 4096; h += 256) {
    float c = bf2f(C1[(size_t)t * 4096 + h]) + b1[h];
    float f0[16], f1[16], g0[16], g1[16];
    load16bf(B1e0 + h * 16, f0);
    load16bf(B1e1 + h * 16, f1);
    load16bf(A2e0 + h * 16, g0);
    load16bf(A2e1 + h * 16, g1);
    float d0 = 0.f, d1 = 0.f;
#pragma unroll
    for (int r = 0; r < 16; ++r) { d0 += lx0[r] * f0[r]; d1 += lx1[r] * f1[r]; }
    float z0 = c + d0, z1 = c + d1;
    float a0 = z0 / (1.f + __expf(-z0));
    float a1 = z1 / (1.f + __expf(-z1));
    am[(size_t)t * 4096 + h] = f2bf(w0 * a0 + w1 * a1);
#pragma unroll
    for (int r = 0; r < 16; ++r) { t0a[r] += a0 * g0[r]; t1a[r] += a1 * g1[r]; }
  }

  const int lane = tid & 63, wv = tid >> 6;
#pragma unroll
  for (int r = 0; r < 16; ++r) {
    float v0 = t0a[r], v1 = t1a[r];
    for (int off = 32; off > 0; off >>= 1) {
      v0 += __shfl_down(v0, off);
      v1 += __shfl_down(v1, off);
    }
    if (lane == 0) { sred[0][wv][r] = v0; sred[1][wv][r] = v1; }
  }
  __syncthreads();
  if (tid < 16)
    T0[t * 16 + tid] = w0 * (sred[0][0][tid] + sred[0][1][tid] + sred[0][2][tid] + sred[0][3][tid]);
  else if (tid < 32) {
    int r = tid - 16;
    T1[t * 16 + r] = w1 * (sred[1][0][r] + sred[1][1][r] + sred[1][2][r] + sred[1][3][r]);
  }
}

// ---------------------------------------------------------------------------
// out = sum_z F2p[z] + b2 + T0 . B2s[e0][d] + T1 . B2s[e1][d]
// ---------------------------------------------------------------------------
__global__ __launch_bounds__(256) void k_final(
    const float* __restrict__ F2p, const float* __restrict__ b2,
    const u16* __restrict__ B2s, const float* __restrict__ T0,
    const float* __restrict__ T1, const int* __restrict__ sel,
    float* __restrict__ out) {
  const int idx = blockIdx.x * 256 + threadIdx.x;
  const int t = idx >> 10, d = idx & 1023;
  const int e0 = sel[2 * t], e1 = sel[2 * t + 1];
  float s = F2p[idx] + F2p[idx + 2097152] + F2p[idx + 4194304] +
            F2p[idx + 6291456] + b2[d];
  float f0[16], f1[16];
  load16bf(B2s + (size_t)e0 * 16384 + d * 16, f0);
  load16bf(B2s + (size_t)e1 * 16384 + d * 16, f1);
  const float* tp0 = T0 + t * 16;
  const float* tp1 = T1 + t * 16;
#pragma unroll
  for (int r = 0; r < 16; ++r) s += tp0[r] * f0[r] + tp1[r] * f1[r];
  out[idx] = s;
}

// ---------------------------------------------------------------------------
extern "C" void kernel_launch(void* const* d_in, const int* in_sizes, int n_in,
                              void* d_out, int out_size, void* d_ws, size_t ws_size,
                              hipStream_t stream) {
  const float* hs   = (const float*)d_in[0];
  const float* gate = (const float*)d_in[1];
  const float* W1   = (const float*)d_in[2];
  const float* b1   = (const float*)d_in[3];
  const float* W2   = (const float*)d_in[4];
  const float* b2   = (const float*)d_in[5];
  const float* A1   = (const float*)d_in[6];
  const float* B1   = (const float*)d_in[7];
  const float* A2   = (const float*)d_in[8];
  const float* B2   = (const float*)d_in[9];

  char* ws = (char*)d_ws;
  size_t off = 0;
  auto alloc = [&](size_t bytes) -> void* {
    void* p = ws + off;
    off += (bytes + 255) & ~(size_t)255;
    return p;
  };
  u16*   Xbf  = (u16*)alloc(2097152ull * 2);        // x bf16 [2048,1024]
  u16*   W1bf = (u16*)alloc(4194304ull * 2);        // [4096,1024]
  u16*   W2bf = (u16*)alloc(4194304ull * 2);        // [1024,4096]
  u16*   A1bf = (u16*)alloc(131072ull * 2);         // [128,1024] (E*R rows)
  u16*   B1s  = (u16*)alloc(524288ull * 2);         // 2*B1 [E,4096,16]
  u16*   B2s  = (u16*)alloc(131072ull * 2);         // 2*B2 [E,1024,16]
  u16*   A2t  = (u16*)alloc(524288ull * 2);         // A2^T [E,4096,16]
  u16*   C1   = (u16*)alloc(2048ull * 4096 * 2);    // x@W1^T bf16
  float* LX   = (float*)alloc(2048ull * 128 * 4);   // x@A1_all^T
  u16*   am   = (u16*)alloc(2048ull * 4096 * 2);    // w0*a0+w1*a1 bf16
  float* F2p  = (float*)alloc(4ull * 2048 * 1024 * 4);  // split-K partials
  float* T0   = (float*)alloc(2048ull * 16 * 4);
  float* T1   = (float*)alloc(2048ull * 16 * 4);
  int*   sel  = (int*)alloc(2048ull * 2 * 4);
  float* wgt  = (float*)alloc(2048ull * 2 * 4);

  k_cvt<<<46080, 256, 0, stream>>>(hs, W1, W2, A1, B1, B2, A2,
                                   Xbf, W1bf, W2bf, A1bf, B1s, B2s, A2t);
  k_router<<<512, 256, 0, stream>>>(hs, gate, sel, wgt);
  // C1 = X @ W1^T  (bf16 out), M=2048 N=4096 K=1024
  gemm_bt<<<dim3(16, 32, 1), 256, 0, stream>>>(Xbf, W1bf, (void*)C1, 1024, 4096, 1024, 0, 1);
  // LX = X @ A1_all^T (fp32 out), N=128
  gemm_bt<<<dim3(16, 1, 1), 256, 0, stream>>>(Xbf, A1bf, (void*)LX, 1024, 128, 1024, 0, 0);
  k_silu<<<2048, 256, 0, stream>>>(C1, LX, b1, B1s, A2t, sel, wgt, am, T0, T1);
  // F2p[z] = am @ W2^T (split-K=4), M=2048 N=1024 K=4096
  gemm_bt<<<dim3(16, 8, 4), 256, 0, stream>>>(am, W2bf, (void*)F2p, 4096, 1024, 1024, 2097152, 0);
  k_final<<<8192, 256, 0, stream>>>(F2p, b2, B2s, T0, T1, sel, (float*)d_out);
}